// Round 12
// baseline (308.310 us; speedup 1.0000x reference)
//
#include <hip/hip_runtime.h>
#include <hip/hip_bf16.h>

// DecoderRNN: B=64, S=32, T=31 decode steps, E=D=512, V=10000
// Pipeline: k_prep(+wlstm, vectorized) -> k_xproj (swapped, vec stores)
//           -> k_rec (R4-proven MALL-sync recurrence + clsw converter)
//           -> k_cls (256x256 tiles: halved L3 read redundancy).

typedef __attribute__((ext_vector_type(4))) float f32x4;
typedef __attribute__((ext_vector_type(8))) short short8;
typedef __attribute__((ext_vector_type(4))) unsigned short u16x4;

#define BB 64
#define SS 32
#define TT 31
#define EE 512
#define VV 10000

__device__ __forceinline__ float sigf(float x){ return 1.0f/(1.0f + __expf(-x)); }
__device__ __forceinline__ float tanh_(float x){
  x = fminf(15.f, fmaxf(-15.f, x));
  float e = __expf(2.f*x);
  return (e-1.f)/(e+1.f);
}
__device__ __forceinline__ unsigned short f2bf(float x){
  __hip_bfloat16 h = __float2bfloat16(x);
  return __builtin_bit_cast(unsigned short, h);
}
__device__ __forceinline__ short8 cvt8(f32x4 a, f32x4 b){
  short8 t;
  t[0] = (short)f2bf(a.x); t[1] = (short)f2bf(a.y);
  t[2] = (short)f2bf(a.z); t[3] = (short)f2bf(a.w);
  t[4] = (short)f2bf(b.x); t[5] = (short)f2bf(b.y);
  t[6] = (short)f2bf(b.z); t[7] = (short)f2bf(b.w);
  return t;
}
// Coherent (MALL-visible) memops — proven R4 helpers.
__device__ __forceinline__ short8 ld16_coh(const void* p){
  short8 r;
  asm volatile("global_load_dwordx4 %0, %1, off sc0 sc1" : "=v"(r) : "v"(p) : "memory");
  return r;
}
__device__ __forceinline__ void st8_coh(void* p, unsigned long long v){
  asm volatile("global_store_dwordx2 %0, %1, off sc0 sc1" :: "v"(p), "v"(v) : "memory");
}

// ---------------------------------------------------------------------------
// Kernel 1: vectorized bf16 conversions (dec_wih, dec_whh) + gathered Xa +
// h0 into hbuf, plus (blocks >= NPREP) the w-LSTM + dl + flag init.
// ---------------------------------------------------------------------------
#define NPREP 2048
__global__ __launch_bounds__(256) void k_prep(
    const float* __restrict__ dwih, const float* __restrict__ dwhh,
    const float* __restrict__ emb, const int* __restrict__ cap,
    const float* __restrict__ enc,
    __hip_bfloat16* __restrict__ wihbf, __hip_bfloat16* __restrict__ whhbf,
    __hip_bfloat16* __restrict__ xa, __hip_bfloat16* __restrict__ h0,
    const int* __restrict__ caplen,
    const float* __restrict__ wwih, const float* __restrict__ wwhh,
    const float* __restrict__ wbih, const float* __restrict__ wbhh,
    const float* __restrict__ ihw, const float* __restrict__ ihb,
    const float* __restrict__ icw, const float* __restrict__ icb,
    float* __restrict__ wgt, unsigned* __restrict__ flags,
    float* __restrict__ dl_out)
{
  if (blockIdx.x >= NPREP){
    // ---- w-LSTM block for batch row b ----
    int b = blockIdx.x - NPREP;
    int w = threadIdx.x >> 6, lane = threadIdx.x & 63;
    __shared__ float sv[6];   // ew[0..3], wh0, wc0

    float p = 0.f;
    for (int k = lane; k < EE; k += 64) p += enc[b*EE + k] * wwih[w*EE + k];
    #pragma unroll
    for (int off = 32; off; off >>= 1) p += __shfl_down(p, off, 64);
    if (lane == 0) sv[w] = p;

    if (w < 2){
      const float* iw = (w == 0) ? ihw : icw;
      float q = 0.f;
      for (int k = lane; k < EE; k += 64) q += enc[b*EE + k] * iw[k];
      #pragma unroll
      for (int off = 32; off; off >>= 1) q += __shfl_down(q, off, 64);
      if (lane == 0) sv[4 + w] = q + ((w == 0) ? ihb[0] : icb[0]);
    }
    __syncthreads();

    if (threadIdx.x == 0){
      float wh = sv[4], wc = sv[5];
      int dl = caplen[b] - 1;
      for (int t = 0; t < TT; t++){
        float gi = sv[0] + wh*wwhh[0] + wbih[0] + wbhh[0];
        float gf = sv[1] + wh*wwhh[1] + wbih[1] + wbhh[1];
        float gg = sv[2] + wh*wwhh[2] + wbih[2] + wbhh[2];
        float go = sv[3] + wh*wwhh[3] + wbih[3] + wbhh[3];
        float wc2 = sigf(gf)*wc + sigf(gi)*tanh_(gg);
        float wh2 = sigf(go)*tanh_(wc2);
        float m = (dl > t) ? 1.f : 0.f;
        wgt[b*TT + t] = sigf(wh2) * m;
        if (dl > t){ wh = wh2; wc = wc2; }
      }
      dl_out[b] = (float)dl;
    }
    if (b == 0) for (int i = threadIdx.x; i < 4096; i += 256) flags[i] = 0;
    return;
  }

  // ---- vectorized conversion blocks (8 elems per iteration) ----
  const int n1 = 262144;               // dec_wih  2,097,152 / 8
  const int n2 = n1 + 131072;          // dec_whh  1,048,576 / 8
  const int n3 = n2 + 253952;          // Xa       2,031,616 / 8
  const int n4 = n3 + 4096;            // h0          32,768 / 8
  for (int i = blockIdx.x*blockDim.x + threadIdx.x; i < n4; i += NPREP*256){
    const float* src; __hip_bfloat16* dst;
    if (i < n1){ src = dwih + (size_t)i*8; dst = wihbf + (size_t)i*8; }
    else if (i < n2){ int j = i - n1; src = dwhh + (size_t)j*8; dst = whhbf + (size_t)j*8; }
    else if (i < n3){
      int j = i - n2; int e = j*8;
      int r = e >> 10, k = e & 1023, t = r >> 6, b = r & 63;
      src = (k < 512) ? emb + (size_t)cap[b*SS + t]*EE + k
                      : enc + (size_t)b*EE + (k - 512);
      dst = xa + (size_t)e;
    } else {
      int j = i - n3; int e = j*8;
      src = enc + (size_t)e; dst = h0 + (size_t)e;
    }
    f32x4 lo = *(const f32x4*)src;
    f32x4 hi = *(const f32x4*)(src + 4);
    *(short8*)dst = cvt8(lo, hi);
  }
}

// ---------------------------------------------------------------------------
// Kernel 2: x-projection GEMM, swapped operands for vector stores.
// ---------------------------------------------------------------------------
__global__ __launch_bounds__(256) void k_xproj(
    const __hip_bfloat16* __restrict__ xa, const __hip_bfloat16* __restrict__ wihbf,
    const float* __restrict__ bih, const float* __restrict__ bhh,
    float* __restrict__ xp)
{
  int bm = blockIdx.y;                 // 0..30 (m0 = bm*64)
  int bn = blockIdx.x;                 // 0..7
  int w = threadIdx.x >> 6, lane = threadIdx.x & 63;
  int col = lane & 15, kg = lane >> 4;
  int m0 = bm*64;
  int n0 = bn*256 + w*64;

  f32x4 acc[4][4] = {};                // [nt][mt]
  for (int kk = 0; kk < 32; kk++){
    short8 aW[4], aX[4];
    #pragma unroll
    for (int i = 0; i < 4; i++){
      aW[i] = *(const short8*)(wihbf + (size_t)(n0 + i*16 + col)*1024 + kk*32 + kg*8);
      aX[i] = *(const short8*)(xa    + (size_t)(m0 + i*16 + col)*1024 + kk*32 + kg*8);
    }
    #pragma unroll
    for (int nt = 0; nt < 4; nt++)
      #pragma unroll
      for (int mt = 0; mt < 4; mt++)
        acc[nt][mt] = __builtin_amdgcn_mfma_f32_16x16x32_bf16(aW[nt], aX[mt], acc[nt][mt], 0, 0, 0);
  }
  #pragma unroll
  for (int nt = 0; nt < 4; nt++){
    int n = n0 + nt*16 + 4*kg;
    f32x4 badd = *(const f32x4*)(bih + n);
    f32x4 b2   = *(const f32x4*)(bhh + n);
    badd = badd + b2;
    #pragma unroll
    for (int mt = 0; mt < 4; mt++){
      int r = m0 + mt*16 + col;
      *(f32x4*)(xp + (size_t)r*2048 + n) = acc[nt][mt] + badd;
    }
  }
}

// ---------------------------------------------------------------------------
// Kernel 3: persistent recurrence (blocks 0..127, 1 wave each) + fused
// cls_w->bf16 conversion (blocks 128..511).  BYTE-EXACT R4 body (135 us).
// ---------------------------------------------------------------------------
__global__ __launch_bounds__(64, 1) void k_rec(
    const __hip_bfloat16* __restrict__ whhbf,   // [2048][512]
    const float* __restrict__ xp,               // [T*64][2048]
    const float* __restrict__ enc,              // [64][512]
    const int* __restrict__ caplen,
    char* __restrict__ hbuf,                    // [2][64][512] bf16 ping-pong
    __hip_bfloat16* __restrict__ hout,          // [64][T][512] b-major
    unsigned* __restrict__ flags,               // 128 lines x 32 u32
    const float* __restrict__ clsw,
    __hip_bfloat16* __restrict__ clsbf)
{
  const int bid = blockIdx.x;
  const int lane = threadIdx.x;

  if (bid >= 128){                     // ---- converter blocks ----
    const int n4 = 1280000;            // 5,120,000 / 4
    for (int i = (bid - 128)*64 + lane; i < n4; i += 384*64){
      f32x4 v = ((const f32x4*)clsw)[i];
      u16x4 o;
      o.x = f2bf(v.x); o.y = f2bf(v.y); o.z = f2bf(v.z); o.w = f2bf(v.w);
      ((u16x4*)clsbf)[i] = o;
    }
    return;
  }

  // ---- recurrence ----
  const int g = bid >> 5, s = bid & 31;
  const int col = lane & 15, kg = lane >> 4;
  const int d0 = s*16;
  const int b  = g*16 + col;           // this lane's batch row
  const int dbase = d0 + 4*kg;         // 4 consecutive d owned by this lane
  const int pme = (dbase >> 2);

  // Persistent A fragments: Whh rows {q*512 + d0 + col}, K=512 (256 regs)
  short8 Aq[4][16];
  #pragma unroll
  for (int q = 0; q < 4; q++){
    const __hip_bfloat16* wrow = whhbf + (size_t)(q*512 + d0 + col)*512;
    #pragma unroll
    for (int kk = 0; kk < 16; kk++)
      Aq[q][kk] = *(const short8*)(wrow + kk*32 + kg*8);
  }
  #pragma unroll
  for (int q = 0; q < 4; q++)
    #pragma unroll
    for (int kk = 0; kk < 16; kk++)
      asm volatile("" : "+v"(Aq[q][kk]));   // pin in registers

  float hst[4], cst[4];
  #pragma unroll
  for (int j = 0; j < 4; j++){
    float e0 = enc[(size_t)b*EE + dbase + j];
    hst[j] = e0; cst[j] = e0;
  }
  const int dl = caplen[b] - 1;
  unsigned* myflag = flags + (size_t)(g*32 + s)*32;
  const unsigned* pollflag = flags + (size_t)(g*32 + (lane & 31))*32;

  f32x4 xg[4];
  #pragma unroll
  for (int q = 0; q < 4; q++)
    xg[q] = *(const f32x4*)(xp + (size_t)b*2048 + q*512 + dbase);

  for (int t = 0; t < TT; t++){
    if (t > 0){
      const unsigned tgt = (unsigned)t;
      while (1){
        unsigned v = __hip_atomic_load(pollflag, __ATOMIC_RELAXED, __HIP_MEMORY_SCOPE_AGENT);
        v = min(v, (unsigned)__shfl_xor((int)v, 1, 64));
        v = min(v, (unsigned)__shfl_xor((int)v, 2, 64));
        v = min(v, (unsigned)__shfl_xor((int)v, 4, 64));
        v = min(v, (unsigned)__shfl_xor((int)v, 8, 64));
        v = min(v, (unsigned)__shfl_xor((int)v, 16, 64));
        if (v >= tgt) break;
        __builtin_amdgcn_s_sleep(1);
      }
    }

    // Issue B-fragment loads (coherent, pipelined)
    const char* hc = hbuf + (size_t)(t & 1)*65536 + (size_t)b*1024 + kg*16;
    short8 Bf[16];
    #pragma unroll
    for (int kk = 0; kk < 16; kk++)
      Bf[kk] = ld16_coh(hc + kk*64);

    // prefetch next step's gate projections (overlaps load latency)
    f32x4 xgn[4];
    if (t + 1 < TT){
      #pragma unroll
      for (int q = 0; q < 4; q++)
        xgn[q] = *(const f32x4*)(xp + (size_t)((t+1)*BB + b)*2048 + q*512 + dbase);
    }

    asm volatile("s_waitcnt vmcnt(0)" ::: "memory");
    __builtin_amdgcn_sched_barrier(0);

    f32x4 acc[4] = {};
    #pragma unroll
    for (int kk = 0; kk < 16; kk++)
      #pragma unroll
      for (int q = 0; q < 4; q++)
        acc[q] = __builtin_amdgcn_mfma_f32_16x16x32_bf16(Aq[q][kk], Bf[kk], acc[q], 0, 0, 0);

    const bool act = dl > t;
    unsigned long long hpack = 0, spack = 0;
    #pragma unroll
    for (int j = 0; j < 4; j++){
      float gi = acc[0][j] + xg[0][j];
      float gf = acc[1][j] + xg[1][j];
      float gg = acc[2][j] + xg[2][j];
      float go = acc[3][j] + xg[3][j];
      float c2 = sigf(gf)*cst[j] + sigf(gi)*tanh_(gg);
      float h2 = sigf(go)*tanh_(c2);
      if (act){ cst[j] = c2; hst[j] = h2; }
      hpack |= (unsigned long long)f2bf(h2)     << (16*j);
      spack |= (unsigned long long)f2bf(hst[j]) << (16*j);
    }

    ((unsigned long long*)hout)[((size_t)b*TT + t)*128 + pme] = hpack;

    if (t < TT - 1){
      st8_coh(hbuf + (size_t)((t + 1) & 1)*65536 + (size_t)b*1024 + (size_t)dbase*2, spack);
      asm volatile("s_waitcnt vmcnt(0)" ::: "memory");
      if (lane == 0)
        __hip_atomic_store(myflag, (unsigned)(t + 1),
                           __ATOMIC_RELAXED, __HIP_MEMORY_SCOPE_AGENT);
    }

    #pragma unroll
    for (int q = 0; q < 4; q++) xg[q] = xgn[q];
  }
}

// ---------------------------------------------------------------------------
// Kernel 4: classifier GEMM, 256x256 block tile (512 threads = 8 waves of
// 64m x 128n). Fragment mapping identical to R11's verified swapped layout:
// lane's acc[i][j] = 4 consecutive v at (n0+i*16+4*kg), row r = m0+j*16+col.
// Halves L3 read redundancy: hbf x40 + wbf x8 = 160 MB (was 318 MB).
// grid 8*40, block 512.
// ---------------------------------------------------------------------------
__global__ __launch_bounds__(512) void k_cls(
    const __hip_bfloat16* __restrict__ hbf,   // [1984][512] (row r = b*31+t)
    const __hip_bfloat16* __restrict__ wbf,   // [10000][512]
    const float* __restrict__ clsb,
    const float* __restrict__ wgt,            // [1984], ==0 iff masked
    float* __restrict__ preds, float* __restrict__ wout)
{
  int bid = blockIdx.x;
  int bn = bid % 40, bm = bid / 40;           // bm 0..7, bn 0..39
  int w = threadIdx.x >> 6, lane = threadIdx.x & 63;
  int col = lane & 15, kg = lane >> 4;
  int mq = w >> 1, nq = w & 1;
  int m0 = bm*256 + mq*64;                    // wave's 64 hbf rows
  int n0 = bn*256 + nq*128;                   // wave's 128 wbf rows

  int vrow[8], rrow[4];
  #pragma unroll
  for (int i = 0; i < 8; i++) vrow[i] = min(n0 + i*16 + col, VV - 1);
  #pragma unroll
  for (int j = 0; j < 4; j++) rrow[j] = min(m0 + j*16 + col, 1983);

  f32x4 acc[8][4] = {};                       // [v-frag][r-frag]
  for (int kk = 0; kk < 16; kk++){
    short8 a[8], b[4];
    #pragma unroll
    for (int i = 0; i < 8; i++)
      a[i] = *(const short8*)(wbf + (size_t)vrow[i]*512 + kk*32 + kg*8);
    #pragma unroll
    for (int j = 0; j < 4; j++)
      b[j] = *(const short8*)(hbf + (size_t)rrow[j]*512 + kk*32 + kg*8);
    #pragma unroll
    for (int i = 0; i < 8; i++)
      #pragma unroll
      for (int j = 0; j < 4; j++)
        acc[i][j] = __builtin_amdgcn_mfma_f32_16x16x32_bf16(a[i], b[j], acc[i][j], 0, 0, 0);
  }

  #pragma unroll
  for (int i = 0; i < 8; i++){
    int v = n0 + i*16 + 4*kg;                 // 4-aligned; VV%4==0 -> clean edge
    if (v >= VV) continue;
    f32x4 cb4 = *(const f32x4*)(clsb + v);
    #pragma unroll
    for (int j = 0; j < 4; j++){
      int r = m0 + j*16 + col;
      if (r >= 1984) continue;
      float wv = wgt[r];
      float mf = (wv > 0.f) ? 1.f : 0.f;
      f32x4 o = (acc[i][j] + cb4) * mf;
      f32x4 wq = {wv, wv, wv, wv};
      *(f32x4*)(preds + (size_t)r*VV + v) = o;
      *(f32x4*)(wout  + (size_t)r*VV + v) = wq;
    }
  }
}

// ---------------------------------------------------------------------------
extern "C" void kernel_launch(void* const* d_in, const int* in_sizes, int n_in,
                              void* d_out, int out_size, void* d_ws, size_t ws_size,
                              hipStream_t stream) {
  const float* enc    = (const float*)d_in[0];
  const int*   cap    = (const int*)  d_in[1];
  const int*   caplen = (const int*)  d_in[2];
  const float* emb    = (const float*)d_in[3];
  const float* dwih   = (const float*)d_in[4];
  const float* dwhh   = (const float*)d_in[5];
  const float* dbih   = (const float*)d_in[6];
  const float* dbhh   = (const float*)d_in[7];
  const float* wwih   = (const float*)d_in[8];
  const float* wwhh   = (const float*)d_in[9];
  const float* wbih   = (const float*)d_in[10];
  const float* wbhh   = (const float*)d_in[11];
  const float* ihw    = (const float*)d_in[12];
  const float* ihb    = (const float*)d_in[13];
  const float* icw    = (const float*)d_in[14];
  const float* icb    = (const float*)d_in[15];
  const float* clsw   = (const float*)d_in[16];
  const float* clsb   = (const float*)d_in[17];

  float* preds  = (float*)d_out;                       // [64][31][10000]
  float* dl_out = preds + (size_t)BB*TT*VV;            // [64]
  float* wout   = dl_out + BB;                         // [64][31][10000]

  char* ws = (char*)d_ws;
  float*          wgt   = (float*)         (ws + 0);          // 1984 f32 (pad 8192)
  unsigned*       flags = (unsigned*)      (ws + 8192);       // 4096 u32 (16 KB)
  __hip_bfloat16* clsbf = (__hip_bfloat16*)(ws + 24576);      // 10,240,000 B
  __hip_bfloat16* wihbf = (__hip_bfloat16*)(ws + 10264576);   //  4,194,304 B
  __hip_bfloat16* whhbf = (__hip_bfloat16*)(ws + 14458880);   //  2,097,152 B
  __hip_bfloat16* xa    = (__hip_bfloat16*)(ws + 16556032);   //  4,063,232 B
  float*          xp    = (float*)         (ws + 20619264);   // 16,252,928 B
  char*           hbuf  = (char*)          (ws + 36872192);   //    131,072 B
  __hip_bfloat16* hout  = (__hip_bfloat16*)(ws + 37003264);   //  2,031,616 B
  // total ~39.0 MB of d_ws

  k_prep <<<NPREP + BB, 256, 0, stream>>>(dwih, dwhh, emb, cap, enc,
                                          wihbf, whhbf, xa,
                                          (__hip_bfloat16*)hbuf,
                                          caplen, wwih, wwhh, wbih, wbhh,
                                          ihw, ihb, icw, icb, wgt, flags, dl_out);
  k_xproj<<<dim3(8, 31), 256, 0, stream>>>(xa, wihbf, dbih, dbhh, xp);
  k_rec  <<<512, 64, 0, stream>>>(whhbf, xp, enc, caplen, hbuf, hout, flags,
                                  clsw, clsbf);
  k_cls  <<<8*40, 512, 0, stream>>>(hout, clsbf, clsb, wgt, preds, wout);
}

// Round 13
// 284.125 us; speedup vs baseline: 1.0851x; 1.0851x over previous
//
#include <hip/hip_runtime.h>
#include <hip/hip_bf16.h>

// DecoderRNN: B=64, S=32, T=31 decode steps, E=D=512, V=10000
// Pipeline: k_prep(+wlstm) -> k_xproj -> k_rec (R4-proven recurrence + clsw
// converter) -> k_cls (preds GEMM, coalesced R4 orientation, 128^2 tiles
//                      + 1984 wout row-broadcast blocks).

typedef __attribute__((ext_vector_type(4))) float f32x4;
typedef __attribute__((ext_vector_type(8))) short short8;
typedef __attribute__((ext_vector_type(4))) unsigned short u16x4;

#define BB 64
#define SS 32
#define TT 31
#define EE 512
#define VV 10000

__device__ __forceinline__ float sigf(float x){ return 1.0f/(1.0f + __expf(-x)); }
__device__ __forceinline__ float tanh_(float x){
  x = fminf(15.f, fmaxf(-15.f, x));
  float e = __expf(2.f*x);
  return (e-1.f)/(e+1.f);
}
__device__ __forceinline__ unsigned short f2bf(float x){
  __hip_bfloat16 h = __float2bfloat16(x);
  return __builtin_bit_cast(unsigned short, h);
}
__device__ __forceinline__ short8 cvt8(f32x4 a, f32x4 b){
  short8 t;
  t[0] = (short)f2bf(a.x); t[1] = (short)f2bf(a.y);
  t[2] = (short)f2bf(a.z); t[3] = (short)f2bf(a.w);
  t[4] = (short)f2bf(b.x); t[5] = (short)f2bf(b.y);
  t[6] = (short)f2bf(b.z); t[7] = (short)f2bf(b.w);
  return t;
}
// Coherent (MALL-visible) memops — proven R4 helpers.
__device__ __forceinline__ short8 ld16_coh(const void* p){
  short8 r;
  asm volatile("global_load_dwordx4 %0, %1, off sc0 sc1" : "=v"(r) : "v"(p) : "memory");
  return r;
}
__device__ __forceinline__ void st8_coh(void* p, unsigned long long v){
  asm volatile("global_store_dwordx2 %0, %1, off sc0 sc1" :: "v"(p), "v"(v) : "memory");
}

// ---------------------------------------------------------------------------
// Kernel 1: vectorized bf16 conversions (dec_wih, dec_whh) + gathered Xa +
// h0 into hbuf, plus (blocks >= NPREP) the w-LSTM + dl + flag init.
// ---------------------------------------------------------------------------
#define NPREP 2048
__global__ __launch_bounds__(256) void k_prep(
    const float* __restrict__ dwih, const float* __restrict__ dwhh,
    const float* __restrict__ emb, const int* __restrict__ cap,
    const float* __restrict__ enc,
    __hip_bfloat16* __restrict__ wihbf, __hip_bfloat16* __restrict__ whhbf,
    __hip_bfloat16* __restrict__ xa, __hip_bfloat16* __restrict__ h0,
    const int* __restrict__ caplen,
    const float* __restrict__ wwih, const float* __restrict__ wwhh,
    const float* __restrict__ wbih, const float* __restrict__ wbhh,
    const float* __restrict__ ihw, const float* __restrict__ ihb,
    const float* __restrict__ icw, const float* __restrict__ icb,
    float* __restrict__ wgt, unsigned* __restrict__ flags,
    float* __restrict__ dl_out)
{
  if (blockIdx.x >= NPREP){
    // ---- w-LSTM block for batch row b ----
    int b = blockIdx.x - NPREP;
    int w = threadIdx.x >> 6, lane = threadIdx.x & 63;
    __shared__ float sv[6];   // ew[0..3], wh0, wc0

    float p = 0.f;
    for (int k = lane; k < EE; k += 64) p += enc[b*EE + k] * wwih[w*EE + k];
    #pragma unroll
    for (int off = 32; off; off >>= 1) p += __shfl_down(p, off, 64);
    if (lane == 0) sv[w] = p;

    if (w < 2){
      const float* iw = (w == 0) ? ihw : icw;
      float q = 0.f;
      for (int k = lane; k < EE; k += 64) q += enc[b*EE + k] * iw[k];
      #pragma unroll
      for (int off = 32; off; off >>= 1) q += __shfl_down(q, off, 64);
      if (lane == 0) sv[4 + w] = q + ((w == 0) ? ihb[0] : icb[0]);
    }
    __syncthreads();

    if (threadIdx.x == 0){
      float wh = sv[4], wc = sv[5];
      int dl = caplen[b] - 1;
      for (int t = 0; t < TT; t++){
        float gi = sv[0] + wh*wwhh[0] + wbih[0] + wbhh[0];
        float gf = sv[1] + wh*wwhh[1] + wbih[1] + wbhh[1];
        float gg = sv[2] + wh*wwhh[2] + wbih[2] + wbhh[2];
        float go = sv[3] + wh*wwhh[3] + wbih[3] + wbhh[3];
        float wc2 = sigf(gf)*wc + sigf(gi)*tanh_(gg);
        float wh2 = sigf(go)*tanh_(wc2);
        float m = (dl > t) ? 1.f : 0.f;
        wgt[b*TT + t] = sigf(wh2) * m;
        if (dl > t){ wh = wh2; wc = wc2; }
      }
      dl_out[b] = (float)dl;
    }
    if (b == 0) for (int i = threadIdx.x; i < 4096; i += 256) flags[i] = 0;
    return;
  }

  // ---- vectorized conversion blocks (8 elems per iteration) ----
  const int n1 = 262144;               // dec_wih  2,097,152 / 8
  const int n2 = n1 + 131072;          // dec_whh  1,048,576 / 8
  const int n3 = n2 + 253952;          // Xa       2,031,616 / 8
  const int n4 = n3 + 4096;            // h0          32,768 / 8
  for (int i = blockIdx.x*blockDim.x + threadIdx.x; i < n4; i += NPREP*256){
    const float* src; __hip_bfloat16* dst;
    if (i < n1){ src = dwih + (size_t)i*8; dst = wihbf + (size_t)i*8; }
    else if (i < n2){ int j = i - n1; src = dwhh + (size_t)j*8; dst = whhbf + (size_t)j*8; }
    else if (i < n3){
      int j = i - n2; int e = j*8;
      int r = e >> 10, k = e & 1023, t = r >> 6, b = r & 63;
      src = (k < 512) ? emb + (size_t)cap[b*SS + t]*EE + k
                      : enc + (size_t)b*EE + (k - 512);
      dst = xa + (size_t)e;
    } else {
      int j = i - n3; int e = j*8;
      src = enc + (size_t)e; dst = h0 + (size_t)e;
    }
    f32x4 lo = *(const f32x4*)src;
    f32x4 hi = *(const f32x4*)(src + 4);
    *(short8*)dst = cvt8(lo, hi);
  }
}

// ---------------------------------------------------------------------------
// Kernel 2: x-projection GEMM, swapped operands for vector stores.
// ---------------------------------------------------------------------------
__global__ __launch_bounds__(256) void k_xproj(
    const __hip_bfloat16* __restrict__ xa, const __hip_bfloat16* __restrict__ wihbf,
    const float* __restrict__ bih, const float* __restrict__ bhh,
    float* __restrict__ xp)
{
  int bm = blockIdx.y;                 // 0..30 (m0 = bm*64)
  int bn = blockIdx.x;                 // 0..7
  int w = threadIdx.x >> 6, lane = threadIdx.x & 63;
  int col = lane & 15, kg = lane >> 4;
  int m0 = bm*64;
  int n0 = bn*256 + w*64;

  f32x4 acc[4][4] = {};                // [nt][mt]
  for (int kk = 0; kk < 32; kk++){
    short8 aW[4], aX[4];
    #pragma unroll
    for (int i = 0; i < 4; i++){
      aW[i] = *(const short8*)(wihbf + (size_t)(n0 + i*16 + col)*1024 + kk*32 + kg*8);
      aX[i] = *(const short8*)(xa    + (size_t)(m0 + i*16 + col)*1024 + kk*32 + kg*8);
    }
    #pragma unroll
    for (int nt = 0; nt < 4; nt++)
      #pragma unroll
      for (int mt = 0; mt < 4; mt++)
        acc[nt][mt] = __builtin_amdgcn_mfma_f32_16x16x32_bf16(aW[nt], aX[mt], acc[nt][mt], 0, 0, 0);
  }
  #pragma unroll
  for (int nt = 0; nt < 4; nt++){
    int n = n0 + nt*16 + 4*kg;
    f32x4 badd = *(const f32x4*)(bih + n);
    f32x4 b2   = *(const f32x4*)(bhh + n);
    badd = badd + b2;
    #pragma unroll
    for (int mt = 0; mt < 4; mt++){
      int r = m0 + mt*16 + col;
      *(f32x4*)(xp + (size_t)r*2048 + n) = acc[nt][mt] + badd;
    }
  }
}

// ---------------------------------------------------------------------------
// Kernel 3: persistent recurrence (blocks 0..127, 1 wave each) + fused
// cls_w->bf16 conversion (blocks 128..511).  BYTE-EXACT R4 body (135 us).
// ---------------------------------------------------------------------------
__global__ __launch_bounds__(64, 1) void k_rec(
    const __hip_bfloat16* __restrict__ whhbf,   // [2048][512]
    const float* __restrict__ xp,               // [T*64][2048]
    const float* __restrict__ enc,              // [64][512]
    const int* __restrict__ caplen,
    char* __restrict__ hbuf,                    // [2][64][512] bf16 ping-pong
    __hip_bfloat16* __restrict__ hout,          // [64][T][512] b-major
    unsigned* __restrict__ flags,               // 128 lines x 32 u32
    const float* __restrict__ clsw,
    __hip_bfloat16* __restrict__ clsbf)
{
  const int bid = blockIdx.x;
  const int lane = threadIdx.x;

  if (bid >= 128){                     // ---- converter blocks ----
    const int n4 = 1280000;            // 5,120,000 / 4
    for (int i = (bid - 128)*64 + lane; i < n4; i += 384*64){
      f32x4 v = ((const f32x4*)clsw)[i];
      u16x4 o;
      o.x = f2bf(v.x); o.y = f2bf(v.y); o.z = f2bf(v.z); o.w = f2bf(v.w);
      ((u16x4*)clsbf)[i] = o;
    }
    return;
  }

  // ---- recurrence ----
  const int g = bid >> 5, s = bid & 31;
  const int col = lane & 15, kg = lane >> 4;
  const int d0 = s*16;
  const int b  = g*16 + col;           // this lane's batch row
  const int dbase = d0 + 4*kg;         // 4 consecutive d owned by this lane
  const int pme = (dbase >> 2);

  // Persistent A fragments: Whh rows {q*512 + d0 + col}, K=512 (256 regs)
  short8 Aq[4][16];
  #pragma unroll
  for (int q = 0; q < 4; q++){
    const __hip_bfloat16* wrow = whhbf + (size_t)(q*512 + d0 + col)*512;
    #pragma unroll
    for (int kk = 0; kk < 16; kk++)
      Aq[q][kk] = *(const short8*)(wrow + kk*32 + kg*8);
  }
  #pragma unroll
  for (int q = 0; q < 4; q++)
    #pragma unroll
    for (int kk = 0; kk < 16; kk++)
      asm volatile("" : "+v"(Aq[q][kk]));   // pin in registers

  float hst[4], cst[4];
  #pragma unroll
  for (int j = 0; j < 4; j++){
    float e0 = enc[(size_t)b*EE + dbase + j];
    hst[j] = e0; cst[j] = e0;
  }
  const int dl = caplen[b] - 1;
  unsigned* myflag = flags + (size_t)(g*32 + s)*32;
  const unsigned* pollflag = flags + (size_t)(g*32 + (lane & 31))*32;

  f32x4 xg[4];
  #pragma unroll
  for (int q = 0; q < 4; q++)
    xg[q] = *(const f32x4*)(xp + (size_t)b*2048 + q*512 + dbase);

  for (int t = 0; t < TT; t++){
    if (t > 0){
      const unsigned tgt = (unsigned)t;
      while (1){
        unsigned v = __hip_atomic_load(pollflag, __ATOMIC_RELAXED, __HIP_MEMORY_SCOPE_AGENT);
        v = min(v, (unsigned)__shfl_xor((int)v, 1, 64));
        v = min(v, (unsigned)__shfl_xor((int)v, 2, 64));
        v = min(v, (unsigned)__shfl_xor((int)v, 4, 64));
        v = min(v, (unsigned)__shfl_xor((int)v, 8, 64));
        v = min(v, (unsigned)__shfl_xor((int)v, 16, 64));
        if (v >= tgt) break;
        __builtin_amdgcn_s_sleep(1);
      }
    }

    // Issue B-fragment loads (coherent, pipelined)
    const char* hc = hbuf + (size_t)(t & 1)*65536 + (size_t)b*1024 + kg*16;
    short8 Bf[16];
    #pragma unroll
    for (int kk = 0; kk < 16; kk++)
      Bf[kk] = ld16_coh(hc + kk*64);

    // prefetch next step's gate projections (overlaps load latency)
    f32x4 xgn[4];
    if (t + 1 < TT){
      #pragma unroll
      for (int q = 0; q < 4; q++)
        xgn[q] = *(const f32x4*)(xp + (size_t)((t+1)*BB + b)*2048 + q*512 + dbase);
    }

    asm volatile("s_waitcnt vmcnt(0)" ::: "memory");
    __builtin_amdgcn_sched_barrier(0);

    f32x4 acc[4] = {};
    #pragma unroll
    for (int kk = 0; kk < 16; kk++)
      #pragma unroll
      for (int q = 0; q < 4; q++)
        acc[q] = __builtin_amdgcn_mfma_f32_16x16x32_bf16(Aq[q][kk], Bf[kk], acc[q], 0, 0, 0);

    const bool act = dl > t;
    unsigned long long hpack = 0, spack = 0;
    #pragma unroll
    for (int j = 0; j < 4; j++){
      float gi = acc[0][j] + xg[0][j];
      float gf = acc[1][j] + xg[1][j];
      float gg = acc[2][j] + xg[2][j];
      float go = acc[3][j] + xg[3][j];
      float c2 = sigf(gf)*cst[j] + sigf(gi)*tanh_(gg);
      float h2 = sigf(go)*tanh_(c2);
      if (act){ cst[j] = c2; hst[j] = h2; }
      hpack |= (unsigned long long)f2bf(h2)     << (16*j);
      spack |= (unsigned long long)f2bf(hst[j]) << (16*j);
    }

    ((unsigned long long*)hout)[((size_t)b*TT + t)*128 + pme] = hpack;

    if (t < TT - 1){
      st8_coh(hbuf + (size_t)((t + 1) & 1)*65536 + (size_t)b*1024 + (size_t)dbase*2, spack);
      asm volatile("s_waitcnt vmcnt(0)" ::: "memory");
      if (lane == 0)
        __hip_atomic_store(myflag, (unsigned)(t + 1),
                           __ATOMIC_RELAXED, __HIP_MEMORY_SCOPE_AGENT);
    }

    #pragma unroll
    for (int q = 0; q < 4; q++) xg[q] = xgn[q];
  }
}

// ---------------------------------------------------------------------------
// Kernel 4: blocks 0..1263: preds GEMM, R4-proven coalesced orientation
// (v = col across lanes -> every store instr fills 4 full 64B lines),
// 128x128 tiles, preds ONLY (half the store work).
// Blocks 1264..3247: wout row-broadcast — one block per output row r,
// 40KB contiguous f32x4 stream (perfectly coalesced, zero reads).
// ---------------------------------------------------------------------------
__global__ __launch_bounds__(256) void k_cls(
    const __hip_bfloat16* __restrict__ hbf,   // [1984][512] (row r = b*31+t)
    const __hip_bfloat16* __restrict__ wbf,   // [10000][512]
    const float* __restrict__ clsb,
    const float* __restrict__ wgt,            // [1984], ==0 iff masked
    float* __restrict__ preds, float* __restrict__ wout)
{
  int bid = blockIdx.x;
  if (bid >= 1264){
    // ---- wout row broadcast ----
    int r = bid - 1264;                       // 0..1983
    float wv = wgt[r];
    f32x4 wq = {wv, wv, wv, wv};
    f32x4* dst = (f32x4*)(wout + (size_t)r*VV);
    #pragma unroll 2
    for (int i = threadIdx.x; i < VV/4; i += 256)
      dst[i] = wq;
    return;
  }

  int bn = bid % 79, bm = bid / 79;
  int w = threadIdx.x >> 6, lane = threadIdx.x & 63;
  int col = lane & 15, kg = lane >> 4;
  int m0 = bm*128 + (w >> 1)*64;
  int n0 = bn*128 + (w & 1)*64;
  if (m0 >= 1984) return;                     // whole wave OOB (no barriers)

  int arow[4], brow[4];
  #pragma unroll
  for (int i = 0; i < 4; i++){
    arow[i] = min(m0 + i*16 + col, 1983);
    brow[i] = min(n0 + i*16 + col, 9999);
  }
  f32x4 acc[4][4] = {};
  for (int kk = 0; kk < 16; kk++){
    short8 a[4], b[4];
    #pragma unroll
    for (int i = 0; i < 4; i++){
      a[i] = *(const short8*)(hbf + (size_t)arow[i]*512 + kk*32 + kg*8);
      b[i] = *(const short8*)(wbf + (size_t)brow[i]*512 + kk*32 + kg*8);
    }
    #pragma unroll
    for (int mt = 0; mt < 4; mt++)
      #pragma unroll
      for (int nt = 0; nt < 4; nt++)
        acc[mt][nt] = __builtin_amdgcn_mfma_f32_16x16x32_bf16(a[mt], b[nt], acc[mt][nt], 0, 0, 0);
  }
  float cb[4]; int vcol[4]; bool vok[4];
  #pragma unroll
  for (int nt = 0; nt < 4; nt++){
    int v = n0 + nt*16 + col; vcol[nt] = v; vok[nt] = (v < VV);
    cb[nt] = vok[nt] ? clsb[v] : 0.f;
  }
  #pragma unroll
  for (int mt = 0; mt < 4; mt++)
    #pragma unroll
    for (int rg = 0; rg < 4; rg++){
      int r = m0 + mt*16 + 4*kg + rg;
      if (r >= 1984) continue;
      float wv = wgt[r];
      float mf = (wv > 0.f) ? 1.f : 0.f;
      size_t base = (size_t)r*VV;
      #pragma unroll
      for (int nt = 0; nt < 4; nt++){
        if (!vok[nt]) continue;
        preds[base + vcol[nt]] = (acc[mt][nt][rg] + cb[nt]) * mf;
      }
    }
}

// ---------------------------------------------------------------------------
extern "C" void kernel_launch(void* const* d_in, const int* in_sizes, int n_in,
                              void* d_out, int out_size, void* d_ws, size_t ws_size,
                              hipStream_t stream) {
  const float* enc    = (const float*)d_in[0];
  const int*   cap    = (const int*)  d_in[1];
  const int*   caplen = (const int*)  d_in[2];
  const float* emb    = (const float*)d_in[3];
  const float* dwih   = (const float*)d_in[4];
  const float* dwhh   = (const float*)d_in[5];
  const float* dbih   = (const float*)d_in[6];
  const float* dbhh   = (const float*)d_in[7];
  const float* wwih   = (const float*)d_in[8];
  const float* wwhh   = (const float*)d_in[9];
  const float* wbih   = (const float*)d_in[10];
  const float* wbhh   = (const float*)d_in[11];
  const float* ihw    = (const float*)d_in[12];
  const float* ihb    = (const float*)d_in[13];
  const float* icw    = (const float*)d_in[14];
  const float* icb    = (const float*)d_in[15];
  const float* clsw   = (const float*)d_in[16];
  const float* clsb   = (const float*)d_in[17];

  float* preds  = (float*)d_out;                       // [64][31][10000]
  float* dl_out = preds + (size_t)BB*TT*VV;            // [64]
  float* wout   = dl_out + BB;                         // [64][31][10000]

  char* ws = (char*)d_ws;
  float*          wgt   = (float*)         (ws + 0);          // 1984 f32 (pad 8192)
  unsigned*       flags = (unsigned*)      (ws + 8192);       // 4096 u32 (16 KB)
  __hip_bfloat16* clsbf = (__hip_bfloat16*)(ws + 24576);      // 10,240,000 B
  __hip_bfloat16* wihbf = (__hip_bfloat16*)(ws + 10264576);   //  4,194,304 B
  __hip_bfloat16* whhbf = (__hip_bfloat16*)(ws + 14458880);   //  2,097,152 B
  __hip_bfloat16* xa    = (__hip_bfloat16*)(ws + 16556032);   //  4,063,232 B
  float*          xp    = (float*)         (ws + 20619264);   // 16,252,928 B
  char*           hbuf  = (char*)          (ws + 36872192);   //    131,072 B
  __hip_bfloat16* hout  = (__hip_bfloat16*)(ws + 37003264);   //  2,031,616 B
  // total ~39.0 MB of d_ws

  k_prep <<<NPREP + BB, 256, 0, stream>>>(dwih, dwhh, emb, cap, enc,
                                          wihbf, whhbf, xa,
                                          (__hip_bfloat16*)hbuf,
                                          caplen, wwih, wwhh, wbih, wbhh,
                                          ihw, ihb, icw, icb, wgt, flags, dl_out);
  k_xproj<<<dim3(8, 31), 256, 0, stream>>>(xa, wihbf, dbih, dbhh, xp);
  k_rec  <<<512, 64, 0, stream>>>(whhbf, xp, enc, caplen, hbuf, hout, flags,
                                  clsw, clsbf);
  k_cls  <<<1264 + 1984, 256, 0, stream>>>(hout, clsbf, clsb, wgt, preds, wout);
}

// Round 14
// 258.307 us; speedup vs baseline: 1.1936x; 1.1000x over previous
//
#include <hip/hip_runtime.h>
#include <hip/hip_bf16.h>

// DecoderRNN: B=64, S=32, T=31 decode steps, E=D=512, V=10000
// Pipeline: k_prep(+wlstm) -> k_xproj -> k_rec (R4-proven recurrence + clsw
// converter) -> k_cls (LDS-staged 128x128 GEMM w/ reg-prefetch dbuf
//                      + 1984 wout row-broadcast blocks).

typedef __attribute__((ext_vector_type(4))) float f32x4;
typedef __attribute__((ext_vector_type(8))) short short8;
typedef __attribute__((ext_vector_type(4))) unsigned short u16x4;

#define BB 64
#define SS 32
#define TT 31
#define EE 512
#define VV 10000

__device__ __forceinline__ float sigf(float x){ return 1.0f/(1.0f + __expf(-x)); }
__device__ __forceinline__ float tanh_(float x){
  x = fminf(15.f, fmaxf(-15.f, x));
  float e = __expf(2.f*x);
  return (e-1.f)/(e+1.f);
}
__device__ __forceinline__ unsigned short f2bf(float x){
  __hip_bfloat16 h = __float2bfloat16(x);
  return __builtin_bit_cast(unsigned short, h);
}
__device__ __forceinline__ short8 cvt8(f32x4 a, f32x4 b){
  short8 t;
  t[0] = (short)f2bf(a.x); t[1] = (short)f2bf(a.y);
  t[2] = (short)f2bf(a.z); t[3] = (short)f2bf(a.w);
  t[4] = (short)f2bf(b.x); t[5] = (short)f2bf(b.y);
  t[6] = (short)f2bf(b.z); t[7] = (short)f2bf(b.w);
  return t;
}
// Coherent (MALL-visible) memops — proven R4 helpers.
__device__ __forceinline__ short8 ld16_coh(const void* p){
  short8 r;
  asm volatile("global_load_dwordx4 %0, %1, off sc0 sc1" : "=v"(r) : "v"(p) : "memory");
  return r;
}
__device__ __forceinline__ void st8_coh(void* p, unsigned long long v){
  asm volatile("global_store_dwordx2 %0, %1, off sc0 sc1" :: "v"(p), "v"(v) : "memory");
}

// ---------------------------------------------------------------------------
// Kernel 1: vectorized bf16 conversions (dec_wih, dec_whh) + gathered Xa +
// h0 into hbuf, plus (blocks >= NPREP) the w-LSTM + dl + flag init.
// ---------------------------------------------------------------------------
#define NPREP 2048
__global__ __launch_bounds__(256) void k_prep(
    const float* __restrict__ dwih, const float* __restrict__ dwhh,
    const float* __restrict__ emb, const int* __restrict__ cap,
    const float* __restrict__ enc,
    __hip_bfloat16* __restrict__ wihbf, __hip_bfloat16* __restrict__ whhbf,
    __hip_bfloat16* __restrict__ xa, __hip_bfloat16* __restrict__ h0,
    const int* __restrict__ caplen,
    const float* __restrict__ wwih, const float* __restrict__ wwhh,
    const float* __restrict__ wbih, const float* __restrict__ wbhh,
    const float* __restrict__ ihw, const float* __restrict__ ihb,
    const float* __restrict__ icw, const float* __restrict__ icb,
    float* __restrict__ wgt, unsigned* __restrict__ flags,
    float* __restrict__ dl_out)
{
  if (blockIdx.x >= NPREP){
    // ---- w-LSTM block for batch row b ----
    int b = blockIdx.x - NPREP;
    int w = threadIdx.x >> 6, lane = threadIdx.x & 63;
    __shared__ float sv[6];   // ew[0..3], wh0, wc0

    float p = 0.f;
    for (int k = lane; k < EE; k += 64) p += enc[b*EE + k] * wwih[w*EE + k];
    #pragma unroll
    for (int off = 32; off; off >>= 1) p += __shfl_down(p, off, 64);
    if (lane == 0) sv[w] = p;

    if (w < 2){
      const float* iw = (w == 0) ? ihw : icw;
      float q = 0.f;
      for (int k = lane; k < EE; k += 64) q += enc[b*EE + k] * iw[k];
      #pragma unroll
      for (int off = 32; off; off >>= 1) q += __shfl_down(q, off, 64);
      if (lane == 0) sv[4 + w] = q + ((w == 0) ? ihb[0] : icb[0]);
    }
    __syncthreads();

    if (threadIdx.x == 0){
      float wh = sv[4], wc = sv[5];
      int dl = caplen[b] - 1;
      for (int t = 0; t < TT; t++){
        float gi = sv[0] + wh*wwhh[0] + wbih[0] + wbhh[0];
        float gf = sv[1] + wh*wwhh[1] + wbih[1] + wbhh[1];
        float gg = sv[2] + wh*wwhh[2] + wbih[2] + wbhh[2];
        float go = sv[3] + wh*wwhh[3] + wbih[3] + wbhh[3];
        float wc2 = sigf(gf)*wc + sigf(gi)*tanh_(gg);
        float wh2 = sigf(go)*tanh_(wc2);
        float m = (dl > t) ? 1.f : 0.f;
        wgt[b*TT + t] = sigf(wh2) * m;
        if (dl > t){ wh = wh2; wc = wc2; }
      }
      dl_out[b] = (float)dl;
    }
    if (b == 0) for (int i = threadIdx.x; i < 4096; i += 256) flags[i] = 0;
    return;
  }

  // ---- vectorized conversion blocks (8 elems per iteration) ----
  const int n1 = 262144;               // dec_wih  2,097,152 / 8
  const int n2 = n1 + 131072;          // dec_whh  1,048,576 / 8
  const int n3 = n2 + 253952;          // Xa       2,031,616 / 8
  const int n4 = n3 + 4096;            // h0          32,768 / 8
  for (int i = blockIdx.x*blockDim.x + threadIdx.x; i < n4; i += NPREP*256){
    const float* src; __hip_bfloat16* dst;
    if (i < n1){ src = dwih + (size_t)i*8; dst = wihbf + (size_t)i*8; }
    else if (i < n2){ int j = i - n1; src = dwhh + (size_t)j*8; dst = whhbf + (size_t)j*8; }
    else if (i < n3){
      int j = i - n2; int e = j*8;
      int r = e >> 10, k = e & 1023, t = r >> 6, b = r & 63;
      src = (k < 512) ? emb + (size_t)cap[b*SS + t]*EE + k
                      : enc + (size_t)b*EE + (k - 512);
      dst = xa + (size_t)e;
    } else {
      int j = i - n3; int e = j*8;
      src = enc + (size_t)e; dst = h0 + (size_t)e;
    }
    f32x4 lo = *(const f32x4*)src;
    f32x4 hi = *(const f32x4*)(src + 4);
    *(short8*)dst = cvt8(lo, hi);
  }
}

// ---------------------------------------------------------------------------
// Kernel 2: x-projection GEMM, swapped operands for vector stores.
// ---------------------------------------------------------------------------
__global__ __launch_bounds__(256) void k_xproj(
    const __hip_bfloat16* __restrict__ xa, const __hip_bfloat16* __restrict__ wihbf,
    const float* __restrict__ bih, const float* __restrict__ bhh,
    float* __restrict__ xp)
{
  int bm = blockIdx.y;                 // 0..30 (m0 = bm*64)
  int bn = blockIdx.x;                 // 0..7
  int w = threadIdx.x >> 6, lane = threadIdx.x & 63;
  int col = lane & 15, kg = lane >> 4;
  int m0 = bm*64;
  int n0 = bn*256 + w*64;

  f32x4 acc[4][4] = {};                // [nt][mt]
  for (int kk = 0; kk < 32; kk++){
    short8 aW[4], aX[4];
    #pragma unroll
    for (int i = 0; i < 4; i++){
      aW[i] = *(const short8*)(wihbf + (size_t)(n0 + i*16 + col)*1024 + kk*32 + kg*8);
      aX[i] = *(const short8*)(xa    + (size_t)(m0 + i*16 + col)*1024 + kk*32 + kg*8);
    }
    #pragma unroll
    for (int nt = 0; nt < 4; nt++)
      #pragma unroll
      for (int mt = 0; mt < 4; mt++)
        acc[nt][mt] = __builtin_amdgcn_mfma_f32_16x16x32_bf16(aW[nt], aX[mt], acc[nt][mt], 0, 0, 0);
  }
  #pragma unroll
  for (int nt = 0; nt < 4; nt++){
    int n = n0 + nt*16 + 4*kg;
    f32x4 badd = *(const f32x4*)(bih + n);
    f32x4 b2   = *(const f32x4*)(bhh + n);
    badd = badd + b2;
    #pragma unroll
    for (int mt = 0; mt < 4; mt++){
      int r = m0 + mt*16 + col;
      *(f32x4*)(xp + (size_t)r*2048 + n) = acc[nt][mt] + badd;
    }
  }
}

// ---------------------------------------------------------------------------
// Kernel 3: persistent recurrence (blocks 0..127, 1 wave each) + fused
// cls_w->bf16 conversion (blocks 128..511).  BYTE-EXACT R4 body (135 us).
// ---------------------------------------------------------------------------
__global__ __launch_bounds__(64, 1) void k_rec(
    const __hip_bfloat16* __restrict__ whhbf,   // [2048][512]
    const float* __restrict__ xp,               // [T*64][2048]
    const float* __restrict__ enc,              // [64][512]
    const int* __restrict__ caplen,
    char* __restrict__ hbuf,                    // [2][64][512] bf16 ping-pong
    __hip_bfloat16* __restrict__ hout,          // [64][T][512] b-major
    unsigned* __restrict__ flags,               // 128 lines x 32 u32
    const float* __restrict__ clsw,
    __hip_bfloat16* __restrict__ clsbf)
{
  const int bid = blockIdx.x;
  const int lane = threadIdx.x;

  if (bid >= 128){                     // ---- converter blocks ----
    const int n4 = 1280000;            // 5,120,000 / 4
    for (int i = (bid - 128)*64 + lane; i < n4; i += 384*64){
      f32x4 v = ((const f32x4*)clsw)[i];
      u16x4 o;
      o.x = f2bf(v.x); o.y = f2bf(v.y); o.z = f2bf(v.z); o.w = f2bf(v.w);
      ((u16x4*)clsbf)[i] = o;
    }
    return;
  }

  // ---- recurrence ----
  const int g = bid >> 5, s = bid & 31;
  const int col = lane & 15, kg = lane >> 4;
  const int d0 = s*16;
  const int b  = g*16 + col;           // this lane's batch row
  const int dbase = d0 + 4*kg;         // 4 consecutive d owned by this lane
  const int pme = (dbase >> 2);

  // Persistent A fragments: Whh rows {q*512 + d0 + col}, K=512 (256 regs)
  short8 Aq[4][16];
  #pragma unroll
  for (int q = 0; q < 4; q++){
    const __hip_bfloat16* wrow = whhbf + (size_t)(q*512 + d0 + col)*512;
    #pragma unroll
    for (int kk = 0; kk < 16; kk++)
      Aq[q][kk] = *(const short8*)(wrow + kk*32 + kg*8);
  }
  #pragma unroll
  for (int q = 0; q < 4; q++)
    #pragma unroll
    for (int kk = 0; kk < 16; kk++)
      asm volatile("" : "+v"(Aq[q][kk]));   // pin in registers

  float hst[4], cst[4];
  #pragma unroll
  for (int j = 0; j < 4; j++){
    float e0 = enc[(size_t)b*EE + dbase + j];
    hst[j] = e0; cst[j] = e0;
  }
  const int dl = caplen[b] - 1;
  unsigned* myflag = flags + (size_t)(g*32 + s)*32;
  const unsigned* pollflag = flags + (size_t)(g*32 + (lane & 31))*32;

  f32x4 xg[4];
  #pragma unroll
  for (int q = 0; q < 4; q++)
    xg[q] = *(const f32x4*)(xp + (size_t)b*2048 + q*512 + dbase);

  for (int t = 0; t < TT; t++){
    if (t > 0){
      const unsigned tgt = (unsigned)t;
      while (1){
        unsigned v = __hip_atomic_load(pollflag, __ATOMIC_RELAXED, __HIP_MEMORY_SCOPE_AGENT);
        v = min(v, (unsigned)__shfl_xor((int)v, 1, 64));
        v = min(v, (unsigned)__shfl_xor((int)v, 2, 64));
        v = min(v, (unsigned)__shfl_xor((int)v, 4, 64));
        v = min(v, (unsigned)__shfl_xor((int)v, 8, 64));
        v = min(v, (unsigned)__shfl_xor((int)v, 16, 64));
        if (v >= tgt) break;
        __builtin_amdgcn_s_sleep(1);
      }
    }

    // Issue B-fragment loads (coherent, pipelined)
    const char* hc = hbuf + (size_t)(t & 1)*65536 + (size_t)b*1024 + kg*16;
    short8 Bf[16];
    #pragma unroll
    for (int kk = 0; kk < 16; kk++)
      Bf[kk] = ld16_coh(hc + kk*64);

    // prefetch next step's gate projections (overlaps load latency)
    f32x4 xgn[4];
    if (t + 1 < TT){
      #pragma unroll
      for (int q = 0; q < 4; q++)
        xgn[q] = *(const f32x4*)(xp + (size_t)((t+1)*BB + b)*2048 + q*512 + dbase);
    }

    asm volatile("s_waitcnt vmcnt(0)" ::: "memory");
    __builtin_amdgcn_sched_barrier(0);

    f32x4 acc[4] = {};
    #pragma unroll
    for (int kk = 0; kk < 16; kk++)
      #pragma unroll
      for (int q = 0; q < 4; q++)
        acc[q] = __builtin_amdgcn_mfma_f32_16x16x32_bf16(Aq[q][kk], Bf[kk], acc[q], 0, 0, 0);

    const bool act = dl > t;
    unsigned long long hpack = 0, spack = 0;
    #pragma unroll
    for (int j = 0; j < 4; j++){
      float gi = acc[0][j] + xg[0][j];
      float gf = acc[1][j] + xg[1][j];
      float gg = acc[2][j] + xg[2][j];
      float go = acc[3][j] + xg[3][j];
      float c2 = sigf(gf)*cst[j] + sigf(gi)*tanh_(gg);
      float h2 = sigf(go)*tanh_(c2);
      if (act){ cst[j] = c2; hst[j] = h2; }
      hpack |= (unsigned long long)f2bf(h2)     << (16*j);
      spack |= (unsigned long long)f2bf(hst[j]) << (16*j);
    }

    ((unsigned long long*)hout)[((size_t)b*TT + t)*128 + pme] = hpack;

    if (t < TT - 1){
      st8_coh(hbuf + (size_t)((t + 1) & 1)*65536 + (size_t)b*1024 + (size_t)dbase*2, spack);
      asm volatile("s_waitcnt vmcnt(0)" ::: "memory");
      if (lane == 0)
        __hip_atomic_store(myflag, (unsigned)(t + 1),
                           __ATOMIC_RELAXED, __HIP_MEMORY_SCOPE_AGENT);
    }

    #pragma unroll
    for (int q = 0; q < 4; q++) xg[q] = xgn[q];
  }
}

// ---------------------------------------------------------------------------
// Kernel 4: blocks 0..1263: preds GEMM, LDS-staged 128x128xBK64 with
// register-prefetch double buffering (m97-style 2-barrier loop).
// LDS rows padded to 72 bf16 (144 B, 16B-aligned, 2-way bank stride).
// Fragment/epilogue mapping byte-identical to R13's verified k_cls.
// Blocks 1264..3247: wout row-broadcast (one row per block, pure stream).
// ---------------------------------------------------------------------------
__global__ __launch_bounds__(256) void k_cls(
    const __hip_bfloat16* __restrict__ hbf,   // [1984][512] (row r = b*31+t)
    const __hip_bfloat16* __restrict__ wbf,   // [10000][512]
    const float* __restrict__ clsb,
    const float* __restrict__ wgt,            // [1984], ==0 iff masked
    float* __restrict__ preds, float* __restrict__ wout)
{
  int bid = blockIdx.x;
  if (bid >= 1264){
    // ---- wout row broadcast ----
    int r = bid - 1264;                       // 0..1983
    float wv = wgt[r];
    f32x4 wq = {wv, wv, wv, wv};
    f32x4* dst = (f32x4*)(wout + (size_t)r*VV);
    #pragma unroll 2
    for (int i = threadIdx.x; i < VV/4; i += 256)
      dst[i] = wq;
    return;
  }

  __shared__ __hip_bfloat16 Ab[128*72];       // 18,432 B (144-B rows)
  __shared__ __hip_bfloat16 Bb[128*72];       // 18,432 B

  int bn = bid % 79, bm = bid / 79;
  int tid = threadIdx.x;
  int w = tid >> 6, lane = tid & 63;
  int col = lane & 15, kg = lane >> 4;

  // staging geometry: seg s = j*256 + tid; row = s&127, kseg = s>>7 (16B units)
  int srow[4], skseg[4]; const __hip_bfloat16 *gA[4], *gB[4];
  #pragma unroll
  for (int j = 0; j < 4; j++){
    int s = j*256 + tid;
    srow[j] = s & 127; skseg[j] = s >> 7;
    gA[j] = hbf + (size_t)min(bm*128 + srow[j], 1983)*512 + skseg[j]*8;
    gB[j] = wbf + (size_t)min(bn*128 + srow[j], 9999)*512 + skseg[j]*8;
  }

  f32x4 acc[4][4] = {};
  short8 rA[4], rB[4];
  #pragma unroll
  for (int j = 0; j < 4; j++){                // prologue: bk=0 loads
    rA[j] = *(const short8*)(gA[j]);
    rB[j] = *(const short8*)(gB[j]);
  }

  for (int bk = 0; bk < 8; bk++){
    __syncthreads();                          // prev compute done
    #pragma unroll
    for (int j = 0; j < 4; j++){
      *(short8*)(Ab + srow[j]*72 + skseg[j]*8) = rA[j];
      *(short8*)(Bb + srow[j]*72 + skseg[j]*8) = rB[j];
    }
    __syncthreads();
    if (bk < 7){                              // prefetch bk+1 (lands under MFMA)
      #pragma unroll
      for (int j = 0; j < 4; j++){
        rA[j] = *(const short8*)(gA[j] + (bk+1)*64);
        rB[j] = *(const short8*)(gB[j] + (bk+1)*64);
      }
    }
    #pragma unroll
    for (int kk2 = 0; kk2 < 2; kk2++){
      short8 a[4], b[4];
      #pragma unroll
      for (int i = 0; i < 4; i++){
        int ra = (w >> 1)*64 + i*16 + col;
        int rb = (w & 1)*64 + i*16 + col;
        a[i] = *(const short8*)(Ab + ra*72 + kk2*32 + kg*8);
        b[i] = *(const short8*)(Bb + rb*72 + kk2*32 + kg*8);
      }
      #pragma unroll
      for (int mt = 0; mt < 4; mt++)
        #pragma unroll
        for (int nt = 0; nt < 4; nt++)
          acc[mt][nt] = __builtin_amdgcn_mfma_f32_16x16x32_bf16(a[mt], b[nt], acc[mt][nt], 0, 0, 0);
    }
  }

  // epilogue — identical mapping to R13
  int m0 = bm*128 + (w >> 1)*64;
  int n0 = bn*128 + (w & 1)*64;
  float cb[4]; int vcol[4]; bool vok[4];
  #pragma unroll
  for (int nt = 0; nt < 4; nt++){
    int v = n0 + nt*16 + col; vcol[nt] = v; vok[nt] = (v < VV);
    cb[nt] = vok[nt] ? clsb[min(v, VV - 1)] : 0.f;
  }
  #pragma unroll
  for (int mt = 0; mt < 4; mt++)
    #pragma unroll
    for (int rg = 0; rg < 4; rg++){
      int r = m0 + mt*16 + 4*kg + rg;
      if (r >= 1984) continue;
      float wv = wgt[r];
      float mf = (wv > 0.f) ? 1.f : 0.f;
      size_t base = (size_t)r*VV;
      #pragma unroll
      for (int nt = 0; nt < 4; nt++){
        if (!vok[nt]) continue;
        preds[base + vcol[nt]] = (acc[mt][nt][rg] + cb[nt]) * mf;
      }
    }
}

// ---------------------------------------------------------------------------
extern "C" void kernel_launch(void* const* d_in, const int* in_sizes, int n_in,
                              void* d_out, int out_size, void* d_ws, size_t ws_size,
                              hipStream_t stream) {
  const float* enc    = (const float*)d_in[0];
  const int*   cap    = (const int*)  d_in[1];
  const int*   caplen = (const int*)  d_in[2];
  const float* emb    = (const float*)d_in[3];
  const float* dwih   = (const float*)d_in[4];
  const float* dwhh   = (const float*)d_in[5];
  const float* dbih   = (const float*)d_in[6];
  const float* dbhh   = (const float*)d_in[7];
  const float* wwih   = (const float*)d_in[8];
  const float* wwhh   = (const float*)d_in[9];
  const float* wbih   = (const float*)d_in[10];
  const float* wbhh   = (const float*)d_in[11];
  const float* ihw    = (const float*)d_in[12];
  const float* ihb    = (const float*)d_in[13];
  const float* icw    = (const float*)d_in[14];
  const float* icb    = (const float*)d_in[15];
  const float* clsw   = (const float*)d_in[16];
  const float* clsb   = (const float*)d_in[17];

  float* preds  = (float*)d_out;                       // [64][31][10000]
  float* dl_out = preds + (size_t)BB*TT*VV;            // [64]
  float* wout   = dl_out + BB;                         // [64][31][10000]

  char* ws = (char*)d_ws;
  float*          wgt   = (float*)         (ws + 0);          // 1984 f32 (pad 8192)
  unsigned*       flags = (unsigned*)      (ws + 8192);       // 4096 u32 (16 KB)
  __hip_bfloat16* clsbf = (__hip_bfloat16*)(ws + 24576);      // 10,240,000 B
  __hip_bfloat16* wihbf = (__hip_bfloat16*)(ws + 10264576);   //  4,194,304 B
  __hip_bfloat16* whhbf = (__hip_bfloat16*)(ws + 14458880);   //  2,097,152 B
  __hip_bfloat16* xa    = (__hip_bfloat16*)(ws + 16556032);   //  4,063,232 B
  float*          xp    = (float*)         (ws + 20619264);   // 16,252,928 B
  char*           hbuf  = (char*)          (ws + 36872192);   //    131,072 B
  __hip_bfloat16* hout  = (__hip_bfloat16*)(ws + 37003264);   //  2,031,616 B
  // total ~39.0 MB of d_ws

  k_prep <<<NPREP + BB, 256, 0, stream>>>(dwih, dwhh, emb, cap, enc,
                                          wihbf, whhbf, xa,
                                          (__hip_bfloat16*)hbuf,
                                          caplen, wwih, wwhh, wbih, wbhh,
                                          ihw, ihb, icw, icb, wgt, flags, dl_out);
  k_xproj<<<dim3(8, 31), 256, 0, stream>>>(xa, wihbf, dbih, dbhh, xp);
  k_rec  <<<512, 64, 0, stream>>>(whhbf, xp, enc, caplen, hbuf, hout, flags,
                                  clsw, clsbf);
  k_cls  <<<1264 + 1984, 256, 0, stream>>>(hout, clsbf, clsb, wgt, preds, wout);
}